// Round 11
// baseline (276.007 us; speedup 1.0000x reference)
//
#include <hip/hip_runtime.h>
#include <cstdint>
#include <cstddef>

#define NNODES 100000
#define DIM 128

#define NB3   (3 * NNODES)
#define BSH   9                        // 512 nodes per bucket
#define NBUCK ((NB3 + 511) >> 9)       // 587 buckets
#define EPB   2048                     // edges per block in binning passes

typedef unsigned short u16;
typedef uint32_t u32;
typedef __attribute__((ext_vector_type(8))) short v8s;
typedef __attribute__((ext_vector_type(4))) float v4f;

__device__ __forceinline__ float bf2f(u32 u) {
  union { u32 i; float f; } x; x.i = u << 16; return x.f;
}
__device__ __forceinline__ u16 f2bf(float f) {
  union { float f; u32 i; } x; x.f = f;
  u32 r = x.i + 0x7fffu + ((x.i >> 16) & 1u);  // RNE
  return (u16)(r >> 16);
}
__device__ __forceinline__ u32 packsplit(float f) {
  u16 h = f2bf(f);
  float r = f - bf2f(h);
  u16 l = f2bf(r);
  return (u32)h | ((u32)l << 16);
}

// =================== bucketed CSR build (3 lists concatenated) ===================

__global__ __launch_bounds__(256) void bin_count(const int* __restrict__ d2u,
    const int* __restrict__ sle, const int* __restrict__ u2d,
    int E1, int E2, int E3, int* __restrict__ bcnt) {
  __shared__ int lc[NBUCK];
  const int tid = threadIdx.x;
  for (int i = tid; i < NBUCK; i += 256) lc[i] = 0;
  __syncthreads();
  const int Etot = E1 + E2 + E3;
  const int base = blockIdx.x * EPB;
#pragma unroll
  for (int k = 0; k < EPB; k += 256) {
    int e = base + k + tid;
    if (e < Etot) {
      int idx;
      if (e < E1)            idx = d2u[E1 + e];
      else if (e < E1 + E2)  idx = NNODES + sle[E2 + (e - E1)];
      else                   idx = 2 * NNODES + u2d[E3 + (e - E1 - E2)];
      atomicAdd(&lc[idx >> BSH], 1);
    }
  }
  __syncthreads();
  for (int i = tid; i < NBUCK; i += 256)
    if (lc[i]) atomicAdd(&bcnt[i], lc[i]);
}

// decode edges; per-block LDS histogram; in-block redundant scan of bcnt
// (replaces the bin_scan dispatch); chunk reservation via gfill (zeroed in
// make_w_planes); write (dst,src) pairs contiguously per bucket.
__global__ __launch_bounds__(256) void bin_fill(const int* __restrict__ d2u,
    const int* __restrict__ sle, const int* __restrict__ u2d,
    int E1, int E2, int E3, const int* __restrict__ bcnt,
    int* __restrict__ gfill, uint2* __restrict__ pairs) {
  __shared__ int lc[NBUCK];   // local count -> chunk cursor
  __shared__ int sc[1024];    // inclusive scan of bcnt
  const int tid = threadIdx.x;
  for (int i = tid; i < NBUCK; i += 256) lc[i] = 0;
  __syncthreads();
  const int Etot = E1 + E2 + E3;
  const int base = blockIdx.x * EPB;
  int vidx[EPB / 256], vsrc[EPB / 256];
#pragma unroll
  for (int k = 0; k < EPB / 256; ++k) {
    int e = base + k * 256 + tid;
    int idx = -1, src = 0;
    if (e < Etot) {
      if (e < E1)            { idx = d2u[E1 + e];                          src = d2u[e]; }
      else if (e < E1 + E2)  { int q = e - E1;      idx = NNODES + sle[E2 + q];      src = sle[q]; }
      else                   { int q = e - E1 - E2; idx = 2 * NNODES + u2d[E3 + q];  src = u2d[q]; }
      atomicAdd(&lc[idx >> BSH], 1);
    }
    vidx[k] = idx; vsrc[k] = src;
  }
  __syncthreads();
  // in-block scan of bcnt -> sc (inclusive)
  for (int i = tid; i < 1024; i += 256) sc[i] = (i < NBUCK) ? bcnt[i] : 0;
  __syncthreads();
  for (int off = 1; off < 1024; off <<= 1) {
    int vals[4];
#pragma unroll
    for (int j = 0; j < 4; ++j) { int i = tid + j * 256; vals[j] = (i >= off) ? sc[i - off] : 0; }
    __syncthreads();
#pragma unroll
    for (int j = 0; j < 4; ++j) { int i = tid + j * 256; sc[i] += vals[j]; }
    __syncthreads();
  }
  // per-block contiguous reservation: brs[i] = sc[i]-bcnt[i]
  for (int i = tid; i < NBUCK; i += 256) {
    int c = lc[i];
    if (c) lc[i] = (sc[i] - bcnt[i]) + atomicAdd(&gfill[i], c);
  }
  __syncthreads();
#pragma unroll
  for (int k = 0; k < EPB / 256; ++k) {
    int idx = vidx[k];
    if (idx >= 0) {
      int pos = atomicAdd(&lc[idx >> BSH], 1);
      pairs[pos] = make_uint2((unsigned)idx, (unsigned)vsrc[k]);
    }
  }
}

// one block per bucket: self-computed bucket base -> histogram -> LDS prefix
// -> cnt/rs/rnorm coalesced -> eidx scatter.
__global__ __launch_bounds__(256) void bucket_build(const uint2* __restrict__ pairs,
    const int* __restrict__ bcnt,
    int* __restrict__ cnt, int* __restrict__ rs, float* __restrict__ rnorm,
    int* __restrict__ eidx) {
  __shared__ int c[512];
  __shared__ int cur[512];
  __shared__ int wsum[4];
  const int tid = threadIdx.x;
  const int b = blockIdx.x;
  // s = sum_{i<b} bcnt[i]
  int part = 0;
  for (int i = tid; i < b; i += 256) part += bcnt[i];
#pragma unroll
  for (int o = 32; o > 0; o >>= 1) part += __shfl_down(part, o, 64);
  if ((tid & 63) == 0) wsum[tid >> 6] = part;
  for (int i = tid; i < 512; i += 256) c[i] = 0;
  __syncthreads();
  const int s = wsum[0] + wsum[1] + wsum[2] + wsum[3];
  const int m = bcnt[b];
  for (int k = tid; k < m; k += 256) {
    uint2 p = pairs[s + k];
    atomicAdd(&c[p.x & 511], 1);
  }
  __syncthreads();
  // exclusive prefix over the bucket's 512 counts (2 per thread + wave scan)
  const int v0 = c[tid * 2], v1 = c[tid * 2 + 1];
  const int tsum = v0 + v1;
  const int lane = tid & 63, wid = tid >> 6;
  int x = tsum;
  for (int off = 1; off < 64; off <<= 1) {
    int y = __shfl_up(x, off, 64);
    if (lane >= off) x += y;
  }
  if (lane == 63) wsum[wid] = x;
  __syncthreads();
  int woff = 0;
  for (int w = 0; w < wid; ++w) woff += wsum[w];
  const int excl = woff + x - tsum;
  const int node0 = b << BSH;
  const int g0 = node0 + tid * 2, g1 = g0 + 1;
  const int r0 = s + excl, r1 = s + excl + v0;
  if (g0 < NB3) {
    cnt[g0] = v0; rs[g0] = r0; cur[tid * 2] = r0;
    if (g0 >= NNODES && g0 < 2 * NNODES) rnorm[g0 - NNODES] = rsqrtf((float)v0 + 1.0f);
  }
  if (g1 < NB3) {
    cnt[g1] = v1; rs[g1] = r1; cur[tid * 2 + 1] = r1;
    if (g1 >= NNODES && g1 < 2 * NNODES) rnorm[g1 - NNODES] = rsqrtf((float)v1 + 1.0f);
  }
  __syncthreads();
  for (int k = tid; k < m; k += 256) {
    uint2 p = pairs[s + k];
    int pos = atomicAdd(&cur[p.x & 511], 1);
    eidx[pos] = (int)p.y;
  }
}

// W planes in FRAGMENT-MAJOR order: slab (kk,ct) of 64 lanes x 8 u16 = 1 KB
// contiguous. Bit-exact same per-lane values as the original LDS layout.
// i bits: [2:0]=j  [8:3]=lane  [11:9]=ct  [13:12]=kk  [15:14]=m
// Also zeroes bcnt[0:1024) + gfill[0:1024) (bbuf[0:2048)).
__global__ void make_w_planes(const float* __restrict__ W0, const float* __restrict__ W1,
                              const float* __restrict__ W2,
                              u16* __restrict__ Whi, u16* __restrict__ Wlo,
                              int* __restrict__ bbuf) {
  int i = blockIdx.x * 256 + threadIdx.x;
  if (i < 2048) bbuf[i] = 0;
  if (i >= 3 * DIM * DIM) return;
  int j = i & 7, lane = (i >> 3) & 63, ct = (i >> 9) & 7, kk = (i >> 12) & 3, m = i >> 14;
  int lr = lane & 15, quad = lane >> 4;
  int c = ct * 16 + lr;            // output col
  int k = kk * 32 + quad * 8 + j;  // K index
  const float* W = (m == 0) ? W0 : ((m == 1) ? W1 : W2);
  u32 p = packsplit(W[k * DIM + c]);
  Whi[i] = (u16)(p & 0xffffu);
  Wlo[i] = (u16)(p >> 16);
}

// =================== gather_gcn ===================

__global__ void gather_gcn(const u16* __restrict__ g,
                           const int* __restrict__ rs, const int* __restrict__ cnt,
                           const int* __restrict__ eidx, const float* __restrict__ rnorm,
                           const float* __restrict__ bias, float* __restrict__ out, int n) {
  int gid = blockIdx.x * 256 + threadIdx.x;
  int i = gid >> 6;
  if (i >= n) return;
  int sub = gid & 63;
  int c = (sub & 31) << 2;
  int start = rs[i], m = cnt[i];
  float4 acc = {0.f, 0.f, 0.f, 0.f};
  if (sub < 32) {   // self term g[i]
    ushort4 pv = *(const ushort4*)(g + ((size_t)i << 7) + c);
    acc.x = bf2f(pv.x); acc.y = bf2f(pv.y);
    acc.z = bf2f(pv.z); acc.w = bf2f(pv.w);
  }
  int j = sub >> 5;
  for (; j + 2 < m; j += 4) {   // two row loads in flight per thread
    int s0 = eidx[start + j], s1 = eidx[start + j + 2];
    ushort4 p0 = *(const ushort4*)(g + ((size_t)s0 << 7) + c);
    ushort4 p1 = *(const ushort4*)(g + ((size_t)s1 << 7) + c);
    acc.x += bf2f(p0.x) + bf2f(p1.x);
    acc.y += bf2f(p0.y) + bf2f(p1.y);
    acc.z += bf2f(p0.z) + bf2f(p1.z);
    acc.w += bf2f(p0.w) + bf2f(p1.w);
  }
  if (j < m) {
    int s = eidx[start + j];
    ushort4 pv = *(const ushort4*)(g + ((size_t)s << 7) + c);
    acc.x += bf2f(pv.x); acc.y += bf2f(pv.y);
    acc.z += bf2f(pv.z); acc.w += bf2f(pv.w);
  }
  acc.x += __shfl_xor(acc.x, 32);
  acc.y += __shfl_xor(acc.y, 32);
  acc.z += __shfl_xor(acc.z, 32);
  acc.w += __shfl_xor(acc.w, 32);
  if (sub < 32) {
    float ri = rnorm[i];
    float4 bv = *(const float4*)(bias + c);
    float4 o;
    o.x = fmaf(ri, acc.x, bv.x);
    o.y = fmaf(ri, acc.y, bv.y);
    o.z = fmaf(ri, acc.z, bv.z);
    o.w = fmaf(ri, acc.w, bv.w);
    *(float4*)(out + (size_t)i * DIM + c) = o;
  }
}

// =================== FUSED stage A + gemm B (v6: two-pass W, 48 KB LDS) ===================
// GEMM1 split into two LDS passes over one 32 KB plane buffer:
//   pass A (Wd-hi): afh*bh + afl*bh ; restage Wd-lo ; pass B: afh*bl.
// All MFMA operands stay in LDS (R6/R9 lesson) with LDS 64->48 KB -> 3 blocks/CU.
// GEMM2 unchanged: Wg-hi LDS x2, Wgl L2 x1 (the one tolerated L2-W read).
__global__ __launch_bounds__(512) void fused_ab(
    const float* __restrict__ emb,
    const int* __restrict__ rs, const int* __restrict__ cnt, const int* __restrict__ eidx,
    const u16* __restrict__ Wdh, const u16* __restrict__ Wdl,
    const u16* __restrict__ Wgh, const u16* __restrict__ Wgl,
    const float* __restrict__ bd, const float* __restrict__ rnorm,
    u16* __restrict__ obf, int nrows)
{
  __shared__ u16 S[24576];            // 48 KB: W plane [0:32K) | X [32K:48K)
  u32* X = (u32*)(S + 16384);
  const int tid = threadIdx.x;
  const int wave = tid >> 6, lane = tid & 63;
  const int lr = lane & 15, quad = lane >> 4;
  const int rowbase = blockIdx.x * 128 + wave * 16;

  int arow = rowbase + lr;
  if (arow >= nrows) arow = nrows - 1;
  const int start = rs[arow], m = cnt[arow];

  // ---- gather-mean(emb) into GEMM1 A-fragments ----
  float4 fa[4], fb[4];
#pragma unroll
  for (int kk = 0; kk < 4; ++kk) {
    fa[kk] = (float4){0.f, 0.f, 0.f, 0.f};
    fb[kk] = (float4){0.f, 0.f, 0.f, 0.f};
  }
  for (int j = 0; j < m; ++j) {
    int s = eidx[start + j];
    const float* rp = emb + (size_t)s * DIM + quad * 8;
#pragma unroll
    for (int kk = 0; kk < 4; ++kk) {
      float4 v0 = *(const float4*)(rp + kk * 32);
      float4 v1 = *(const float4*)(rp + kk * 32 + 4);
      fa[kk].x += v0.x; fa[kk].y += v0.y; fa[kk].z += v0.z; fa[kk].w += v0.w;
      fb[kk].x += v1.x; fb[kk].y += v1.y; fb[kk].z += v1.z; fb[kk].w += v1.w;
    }
  }
  const float inv = 1.0f / fmaxf((float)m, 1.0f);
  v8s afh[4], afl[4];
#pragma unroll
  for (int kk = 0; kk < 4; ++kk) {
    float vs[8] = {fa[kk].x, fa[kk].y, fa[kk].z, fa[kk].w,
                   fb[kk].x, fb[kk].y, fb[kk].z, fb[kk].w};
#pragma unroll
    for (int j = 0; j < 8; ++j) {
      u32 p = packsplit(vs[j] * inv);
      afh[kk][j] = (short)(p & 0xffffu);
      afl[kk][j] = (short)(p >> 16);
    }
  }

  // ---- stage Wd-hi (32 KB) ----
  {
    uint4* S4 = (uint4*)S;
    for (int i = tid; i < 2048; i += 512)
      S4[i] = ((const uint4*)Wdh)[i];
  }
  __syncthreads();

  // ---- GEMM1 pass A: afh*bh + afl*bh ----
  v4f acc[8];
#pragma unroll
  for (int ct = 0; ct < 8; ++ct) acc[ct] = (v4f){0.f, 0.f, 0.f, 0.f};
#pragma unroll
  for (int kk = 0; kk < 4; ++kk) {
#pragma unroll
    for (int ct = 0; ct < 8; ++ct) {
      const int wo = ((kk * 8 + ct) << 9) + (lane << 3);
      v8s bh = *(const v8s*)(S + wo);
      acc[ct] = __builtin_amdgcn_mfma_f32_16x16x32_bf16(afh[kk], bh, acc[ct], 0, 0, 0);
      acc[ct] = __builtin_amdgcn_mfma_f32_16x16x32_bf16(afl[kk], bh, acc[ct], 0, 0, 0);
    }
  }
  __syncthreads();   // Wd-hi dead

  // ---- restage Wd-lo; GEMM1 pass B: afh*bl ----
  {
    uint4* S4 = (uint4*)S;
    for (int i = tid; i < 2048; i += 512)
      S4[i] = ((const uint4*)Wdl)[i];
  }
  __syncthreads();
#pragma unroll
  for (int kk = 0; kk < 4; ++kk) {
#pragma unroll
    for (int ct = 0; ct < 8; ++ct) {
      const int wo = ((kk * 8 + ct) << 9) + (lane << 3);
      v8s bl = *(const v8s*)(S + wo);
      acc[ct] = __builtin_amdgcn_mfma_f32_16x16x32_bf16(afh[kk], bl, acc[ct], 0, 0, 0);
    }
  }
  __syncthreads();   // Wd-lo dead

  // ---- restage Wg-hi into [0:32K) ----
  {
    uint4* S4 = (uint4*)S;
    for (int i = tid; i < 2048; i += 512)
      S4[i] = ((const uint4*)Wgh)[i];
  }

  // ---- x1 quarter 0: x1 = relu(emb + agg1@Wd + bd), cols [0,32) ----
#pragma unroll
  for (int cl = 0; cl < 2; ++cl) {
#pragma unroll
    for (int rg = 0; rg < 4; ++rg) {
      int r = rowbase + quad * 4 + rg;
      int rc = (r < nrows) ? r : (nrows - 1);
      const int col = cl * 16 + lr;
      float v = acc[cl][rg] + bd[col] + emb[(size_t)rc * DIM + col];
      v = fmaxf(v, 0.f);
      int slot = ((rg << 1) | cl) * 64 + (quad << 4) + lr;
      slot ^= ((slot >> 6) & 7) << 2;
      X[wave * 512 + slot] = packsplit(v);
    }
  }
  __syncthreads();   // Wg-hi visible to all waves

  // ---- GEMM2: x1@Wg in 4 K-slices, x1 through LDS quarters ----
  v4f acc2[8];
#pragma unroll
  for (int ct = 0; ct < 8; ++ct) acc2[ct] = (v4f){0.f, 0.f, 0.f, 0.f};
#pragma unroll
  for (int Q = 0; Q < 4; ++Q) {
    // reload kk=Q A-fragments from this wave's private quarter slot
    v8s agh, agl;
    {
      int s0 = ((lr & 3) * 2 + (quad >> 1)) * 64 + ((lr >> 2) << 4) + ((quad & 1) << 3);
      int s1 = s0 + 4;
      s0 ^= ((s0 >> 6) & 7) << 2;
      s1 ^= ((s1 >> 6) & 7) << 2;
      uint4 q0 = *(const uint4*)(X + wave * 512 + s0);
      uint4 q1 = *(const uint4*)(X + wave * 512 + s1);
      u32 u[8] = {q0.x, q0.y, q0.z, q0.w, q1.x, q1.y, q1.z, q1.w};
#pragma unroll
      for (int j = 0; j < 8; ++j) {
        agh[j] = (short)(u[j] & 0xffffu);
        agl[j] = (short)(u[j] >> 16);
      }
    }
#pragma unroll
    for (int ct = 0; ct < 8; ++ct) {
      const int wo = ((Q * 8 + ct) << 9) + (lane << 3);
      v8s bh = *(const v8s*)(S + wo);
      v8s bl = *(const v8s*)(Wgl + wo);
      acc2[ct] = __builtin_amdgcn_mfma_f32_16x16x32_bf16(agh, bh, acc2[ct], 0, 0, 0);
      acc2[ct] = __builtin_amdgcn_mfma_f32_16x16x32_bf16(agh, bl, acc2[ct], 0, 0, 0);
      acc2[ct] = __builtin_amdgcn_mfma_f32_16x16x32_bf16(agl, bh, acc2[ct], 0, 0, 0);
    }
    if (Q < 3) {   // write next quarter (wave-private slot; same-wave DS order)
#pragma unroll
      for (int cl = 0; cl < 2; ++cl) {
        int ct = 2 * (Q + 1) + cl;
#pragma unroll
        for (int rg = 0; rg < 4; ++rg) {
          int r = rowbase + quad * 4 + rg;
          int rc = (r < nrows) ? r : (nrows - 1);
          const int col = ct * 16 + lr;
          float v = acc[ct][rg] + bd[col] + emb[(size_t)rc * DIM + col];
          v = fmaxf(v, 0.f);
          int slot = ((rg << 1) | cl) * 64 + (quad << 4) + lr;
          slot ^= ((slot >> 6) & 7) << 2;
          X[wave * 512 + slot] = packsplit(v);
        }
      }
    }
  }

  __syncthreads();   // all GEMM2 LDS reads done; reuse S[0:32K) as transpose buf

  // ---- epilogue: g = rnorm.*(x1@Wg) -> bf16 row-major via swizzled transpose ----
  const int lrow0 = wave * 16 + quad * 4;
#pragma unroll
  for (int rg = 0; rg < 4; ++rg) {
    int lrow = lrow0 + rg;
    int r = blockIdx.x * 128 + lrow;
    float sc = rnorm[(r < nrows) ? r : (nrows - 1)];
    const int swz = (lrow & 7) << 4;
#pragma unroll
    for (int ct = 0; ct < 8; ++ct) {
      const int col = ct * 16 + lr;
      S[(lrow << 7) + (col ^ swz)] = f2bf(acc2[ct][rg] * sc);
    }
  }
  __syncthreads();
  const int rowstart = blockIdx.x * 128;
  for (int idx = tid; idx < 2048; idx += 512) {   // 2048 uint4 row stores
    int lrow = idx >> 4, c8 = (idx & 15) << 3;
    int r = rowstart + lrow;
    if (r < nrows) {
      uint4 v = *(const uint4*)&S[(lrow << 7) + (c8 ^ ((lrow & 7) << 4))];
      *(uint4*)(obf + ((size_t)r << 7) + c8) = v;
    }
  }
}

// =================== FUSED stage C (v2: two-pass W, 32 KB LDS -> 4 blocks/CU) ===================
__global__ __launch_bounds__(512) void gather_gemm_c(
    const float* __restrict__ x,
    const int* __restrict__ rs, const int* __restrict__ cnt, const int* __restrict__ eidx,
    const u16* __restrict__ Wuh, const u16* __restrict__ Wul,
    const float* __restrict__ bias, float* __restrict__ outf, int nrows)
{
  __shared__ u16 W[DIM * DIM];   // 32 KB: one plane at a time, fragment-major
  const int tid = threadIdx.x;
  const int wave = tid >> 6, lane = tid & 63;
  const int lr = lane & 15, quad = lane >> 4;
  const int rowbase = blockIdx.x * 128 + wave * 16;

  int arow = rowbase + lr;
  if (arow >= nrows) arow = nrows - 1;
  const int start = rs[arow], m = cnt[arow];

  float4 fa[4], fb[4];
#pragma unroll
  for (int kk = 0; kk < 4; ++kk) {
    fa[kk] = (float4){0.f, 0.f, 0.f, 0.f};
    fb[kk] = (float4){0.f, 0.f, 0.f, 0.f};
  }
  for (int j = 0; j < m; ++j) {
    int s = eidx[start + j];
    const float* rp = x + (size_t)s * DIM + quad * 8;
#pragma unroll
    for (int kk = 0; kk < 4; ++kk) {
      float4 v0 = *(const float4*)(rp + kk * 32);
      float4 v1 = *(const float4*)(rp + kk * 32 + 4);
      fa[kk].x += v0.x; fa[kk].y += v0.y; fa[kk].z += v0.z; fa[kk].w += v0.w;
      fb[kk].x += v1.x; fb[kk].y += v1.y; fb[kk].z += v1.z; fb[kk].w += v1.w;
    }
  }
  const float inv = 1.0f / fmaxf((float)m, 1.0f);
  v8s afh[4], afl[4];
#pragma unroll
  for (int kk = 0; kk < 4; ++kk) {
    float vs[8] = {fa[kk].x, fa[kk].y, fa[kk].z, fa[kk].w,
                   fb[kk].x, fb[kk].y, fb[kk].z, fb[kk].w};
#pragma unroll
    for (int j = 0; j < 8; ++j) {
      u32 p = packsplit(vs[j] * inv);
      afh[kk][j] = (short)(p & 0xffffu);
      afl[kk][j] = (short)(p >> 16);
    }
  }

  // ---- stage Wu-hi; pass A: afh*bh + afl*bh ----
  {
    uint4* W4 = (uint4*)W;
    for (int i = tid; i < 2048; i += 512)
      W4[i] = ((const uint4*)Wuh)[i];
  }
  __syncthreads();

  v4f acc[8];
#pragma unroll
  for (int ct = 0; ct < 8; ++ct) acc[ct] = (v4f){0.f, 0.f, 0.f, 0.f};
#pragma unroll
  for (int kk = 0; kk < 4; ++kk) {
#pragma unroll
    for (int ct = 0; ct < 8; ++ct) {
      const int wo = ((kk * 8 + ct) << 9) + (lane << 3);
      v8s bh = *(const v8s*)(W + wo);
      acc[ct] = __builtin_amdgcn_mfma_f32_16x16x32_bf16(afh[kk], bh, acc[ct], 0, 0, 0);
      acc[ct] = __builtin_amdgcn_mfma_f32_16x16x32_bf16(afl[kk], bh, acc[ct], 0, 0, 0);
    }
  }
  __syncthreads();

  // ---- restage Wu-lo; pass B: afh*bl ----
  {
    uint4* W4 = (uint4*)W;
    for (int i = tid; i < 2048; i += 512)
      W4[i] = ((const uint4*)Wul)[i];
  }
  __syncthreads();
#pragma unroll
  for (int kk = 0; kk < 4; ++kk) {
#pragma unroll
    for (int ct = 0; ct < 8; ++ct) {
      const int wo = ((kk * 8 + ct) << 9) + (lane << 3);
      v8s bl = *(const v8s*)(W + wo);
      acc[ct] = __builtin_amdgcn_mfma_f32_16x16x32_bf16(afh[kk], bl, acc[ct], 0, 0, 0);
    }
  }

#pragma unroll
  for (int ct = 0; ct < 8; ++ct) {
    const int col = ct * 16 + lr;
    float bv = bias[col];
#pragma unroll
    for (int rg = 0; rg < 4; ++rg) {
      int r = rowbase + quad * 4 + rg;
      if (r < nrows) {
        size_t off = (size_t)r * DIM + col;
        float v = acc[ct][rg] + bv + x[off];
        outf[off] = fmaxf(v, 0.f);
      }
    }
  }
}

// =================== host ===================

extern "C" void kernel_launch(void* const* d_in, const int* in_sizes, int n_in,
                              void* d_out, int out_size, void* d_ws, size_t ws_size,
                              hipStream_t stream) {
  const float* emb = (const float*)d_in[0];
  const float* Wd  = (const float*)d_in[1];
  const float* bd  = (const float*)d_in[2];
  const float* Wg  = (const float*)d_in[3];
  const float* bg  = (const float*)d_in[4];
  const float* Wu  = (const float*)d_in[5];
  const float* bu  = (const float*)d_in[6];
  const int* d2u = (const int*)d_in[7];
  const int* sle = (const int*)d_in[8];
  const int* u2d = (const int*)d_in[9];
  const int E1 = in_sizes[7] / 2;   // 100000
  const int E2 = in_sizes[8] / 2;   // 600000
  const int E3 = in_sizes[9] / 2;   // 100000
  const int Etot = E1 + E2 + E3;
  const int N  = NNODES;
  const size_t nd = (size_t)N * DIM;

  float* xb = (float*)d_ws;        // f32 x2 plane (51.2 MB)
  u16* Gbf  = (u16*)(xb + nd);     // row-major bf16 g plane [nd u16] (25.6 MB)
  int* cnt  = (int*)(Gbf + nd);    // [3N]
  int* bbuf = cnt + 3 * N;         // bucket arrays: bcnt(1024) | gfill(1024) | spare
  int* rs   = bbuf + 3 * 1024;     // [3N]
  int* eidx = rs + 3 * N;          // [Etot]
  float* rnorm = (float*)(eidx + Etot);
  int* bsum = (int*)(rnorm + N);   // unused (layout stability)
  u16* Whi = (u16*)(bsum + 1024);
  u16* Wlo = Whi + 3 * DIM * DIM;
  uint2* pairs = (uint2*)(Wlo + 3 * DIM * DIM);   // [Etot] (6.4 MB)
  int* bcnt  = bbuf;
  int* gfill = bbuf + 1024;

  const int gemm_blocks = (N + 127) / 128;        // 782
  const int ngcn = (N * 64 + 255) / 256;          // 25000 (64 t/node)
  const int nbin = (Etot + EPB - 1) / EPB;        // 391

  // ---- prep (4 dispatches): W planes (+bbuf zero) + bucketed CSR ----
  make_w_planes<<<(3 * DIM * DIM + 255) / 256, 256, 0, stream>>>(Wd, Wg, Wu, Whi, Wlo, bbuf);
  bin_count<<<nbin, 256, 0, stream>>>(d2u, sle, u2d, E1, E2, E3, bcnt);
  bin_fill<<<nbin, 256, 0, stream>>>(d2u, sle, u2d, E1, E2, E3, bcnt, gfill, pairs);
  bucket_build<<<NBUCK, 256, 0, stream>>>(pairs, bcnt, cnt, rs, rnorm, eidx);

  // ---- fused A+B: x1 (LDS-only) ; g = rnorm.*(x1@Wg) -> Gbf ----
  fused_ab<<<gemm_blocks, 512, 0, stream>>>(emb, rs, cnt, eidx,
                                            Whi, Wlo, Whi + DIM * DIM, Wlo + DIM * DIM,
                                            bd, rnorm, Gbf, N);

  // ---- gcn gather: x2 -> xb ----
  gather_gcn<<<ngcn, 256, 0, stream>>>(Gbf, rs + N, cnt + N, eidx, rnorm, bg, xb, N);

  // ---- fused C: out = relu(x2 + mean_gather(x2)@Wu + bu) -> d_out ----
  gather_gemm_c<<<gemm_blocks, 512, 0, stream>>>(xb, rs + 2 * N, cnt + 2 * N, eidx,
                                                 Whi + 2 * DIM * DIM, Wlo + 2 * DIM * DIM,
                                                 bu, (float*)d_out, N);
}

// Round 12
// 272.397 us; speedup vs baseline: 1.0133x; 1.0133x over previous
//
#include <hip/hip_runtime.h>
#include <cstdint>
#include <cstddef>

#define NNODES 100000
#define DIM 128

#define NB3   (3 * NNODES)
#define BSH   9                        // 512 nodes per bucket
#define NBUCK ((NB3 + 511) >> 9)       // 587 buckets
#define EPB   2048                     // edges per block in binning passes

typedef unsigned short u16;
typedef uint32_t u32;
typedef __attribute__((ext_vector_type(8))) short v8s;
typedef __attribute__((ext_vector_type(4))) float v4f;

__device__ __forceinline__ float bf2f(u32 u) {
  union { u32 i; float f; } x; x.i = u << 16; return x.f;
}
__device__ __forceinline__ u16 f2bf(float f) {
  union { float f; u32 i; } x; x.f = f;
  u32 r = x.i + 0x7fffu + ((x.i >> 16) & 1u);  // RNE
  return (u16)(r >> 16);
}
__device__ __forceinline__ u32 packsplit(float f) {
  u16 h = f2bf(f);
  float r = f - bf2f(h);
  u16 l = f2bf(r);
  return (u32)h | ((u32)l << 16);
}

// =================== bucketed CSR build (3 lists concatenated) ===================

__global__ __launch_bounds__(256) void bin_count(const int* __restrict__ d2u,
    const int* __restrict__ sle, const int* __restrict__ u2d,
    int E1, int E2, int E3, int* __restrict__ bcnt) {
  __shared__ int lc[NBUCK];
  const int tid = threadIdx.x;
  for (int i = tid; i < NBUCK; i += 256) lc[i] = 0;
  __syncthreads();
  const int Etot = E1 + E2 + E3;
  const int base = blockIdx.x * EPB;
#pragma unroll
  for (int k = 0; k < EPB; k += 256) {
    int e = base + k + tid;
    if (e < Etot) {
      int idx;
      if (e < E1)            idx = d2u[E1 + e];
      else if (e < E1 + E2)  idx = NNODES + sle[E2 + (e - E1)];
      else                   idx = 2 * NNODES + u2d[E3 + (e - E1 - E2)];
      atomicAdd(&lc[idx >> BSH], 1);
    }
  }
  __syncthreads();
  for (int i = tid; i < NBUCK; i += 256)
    if (lc[i]) atomicAdd(&bcnt[i], lc[i]);
}

// decode edges; per-block LDS histogram; in-block redundant scan of bcnt
// (replaces the bin_scan dispatch); chunk reservation via gfill (zeroed in
// make_w_planes); write (dst,src) pairs contiguously per bucket.
__global__ __launch_bounds__(256) void bin_fill(const int* __restrict__ d2u,
    const int* __restrict__ sle, const int* __restrict__ u2d,
    int E1, int E2, int E3, const int* __restrict__ bcnt,
    int* __restrict__ gfill, uint2* __restrict__ pairs) {
  __shared__ int lc[NBUCK];   // local count -> chunk cursor
  __shared__ int sc[1024];    // inclusive scan of bcnt
  const int tid = threadIdx.x;
  for (int i = tid; i < NBUCK; i += 256) lc[i] = 0;
  __syncthreads();
  const int Etot = E1 + E2 + E3;
  const int base = blockIdx.x * EPB;
  int vidx[EPB / 256], vsrc[EPB / 256];
#pragma unroll
  for (int k = 0; k < EPB / 256; ++k) {
    int e = base + k * 256 + tid;
    int idx = -1, src = 0;
    if (e < Etot) {
      if (e < E1)            { idx = d2u[E1 + e];                          src = d2u[e]; }
      else if (e < E1 + E2)  { int q = e - E1;      idx = NNODES + sle[E2 + q];      src = sle[q]; }
      else                   { int q = e - E1 - E2; idx = 2 * NNODES + u2d[E3 + q];  src = u2d[q]; }
      atomicAdd(&lc[idx >> BSH], 1);
    }
    vidx[k] = idx; vsrc[k] = src;
  }
  __syncthreads();
  // in-block scan of bcnt -> sc (inclusive)
  for (int i = tid; i < 1024; i += 256) sc[i] = (i < NBUCK) ? bcnt[i] : 0;
  __syncthreads();
  for (int off = 1; off < 1024; off <<= 1) {
    int vals[4];
#pragma unroll
    for (int j = 0; j < 4; ++j) { int i = tid + j * 256; vals[j] = (i >= off) ? sc[i - off] : 0; }
    __syncthreads();
#pragma unroll
    for (int j = 0; j < 4; ++j) { int i = tid + j * 256; sc[i] += vals[j]; }
    __syncthreads();
  }
  // per-block contiguous reservation: brs[i] = sc[i]-bcnt[i]
  for (int i = tid; i < NBUCK; i += 256) {
    int c = lc[i];
    if (c) lc[i] = (sc[i] - bcnt[i]) + atomicAdd(&gfill[i], c);
  }
  __syncthreads();
#pragma unroll
  for (int k = 0; k < EPB / 256; ++k) {
    int idx = vidx[k];
    if (idx >= 0) {
      int pos = atomicAdd(&lc[idx >> BSH], 1);
      pairs[pos] = make_uint2((unsigned)idx, (unsigned)vsrc[k]);
    }
  }
}

// one block per bucket: self-computed bucket base -> histogram -> LDS prefix
// -> cnt/rs/rnorm coalesced -> eidx scatter.
__global__ __launch_bounds__(256) void bucket_build(const uint2* __restrict__ pairs,
    const int* __restrict__ bcnt,
    int* __restrict__ cnt, int* __restrict__ rs, float* __restrict__ rnorm,
    int* __restrict__ eidx) {
  __shared__ int c[512];
  __shared__ int cur[512];
  __shared__ int wsum[4];
  const int tid = threadIdx.x;
  const int b = blockIdx.x;
  // s = sum_{i<b} bcnt[i]
  int part = 0;
  for (int i = tid; i < b; i += 256) part += bcnt[i];
#pragma unroll
  for (int o = 32; o > 0; o >>= 1) part += __shfl_down(part, o, 64);
  if ((tid & 63) == 0) wsum[tid >> 6] = part;
  for (int i = tid; i < 512; i += 256) c[i] = 0;
  __syncthreads();
  const int s = wsum[0] + wsum[1] + wsum[2] + wsum[3];
  const int m = bcnt[b];
  for (int k = tid; k < m; k += 256) {
    uint2 p = pairs[s + k];
    atomicAdd(&c[p.x & 511], 1);
  }
  __syncthreads();
  // exclusive prefix over the bucket's 512 counts (2 per thread + wave scan)
  const int v0 = c[tid * 2], v1 = c[tid * 2 + 1];
  const int tsum = v0 + v1;
  const int lane = tid & 63, wid = tid >> 6;
  int x = tsum;
  for (int off = 1; off < 64; off <<= 1) {
    int y = __shfl_up(x, off, 64);
    if (lane >= off) x += y;
  }
  if (lane == 63) wsum[wid] = x;
  __syncthreads();
  int woff = 0;
  for (int w = 0; w < wid; ++w) woff += wsum[w];
  const int excl = woff + x - tsum;
  const int node0 = b << BSH;
  const int g0 = node0 + tid * 2, g1 = g0 + 1;
  const int r0 = s + excl, r1 = s + excl + v0;
  if (g0 < NB3) {
    cnt[g0] = v0; rs[g0] = r0; cur[tid * 2] = r0;
    if (g0 >= NNODES && g0 < 2 * NNODES) rnorm[g0 - NNODES] = rsqrtf((float)v0 + 1.0f);
  }
  if (g1 < NB3) {
    cnt[g1] = v1; rs[g1] = r1; cur[tid * 2 + 1] = r1;
    if (g1 >= NNODES && g1 < 2 * NNODES) rnorm[g1 - NNODES] = rsqrtf((float)v1 + 1.0f);
  }
  __syncthreads();
  for (int k = tid; k < m; k += 256) {
    uint2 p = pairs[s + k];
    int pos = atomicAdd(&cur[p.x & 511], 1);
    eidx[pos] = (int)p.y;
  }
}

// W planes in FRAGMENT-MAJOR order: slab (kk,ct) of 64 lanes x 8 u16 = 1 KB
// contiguous. Bit-exact same per-lane values as the original LDS layout.
// i bits: [2:0]=j  [8:3]=lane  [11:9]=ct  [13:12]=kk  [15:14]=m
// Also zeroes bcnt[0:1024) + gfill[0:1024) (bbuf[0:2048)).
__global__ void make_w_planes(const float* __restrict__ W0, const float* __restrict__ W1,
                              const float* __restrict__ W2,
                              u16* __restrict__ Whi, u16* __restrict__ Wlo,
                              int* __restrict__ bbuf) {
  int i = blockIdx.x * 256 + threadIdx.x;
  if (i < 2048) bbuf[i] = 0;
  if (i >= 3 * DIM * DIM) return;
  int j = i & 7, lane = (i >> 3) & 63, ct = (i >> 9) & 7, kk = (i >> 12) & 3, m = i >> 14;
  int lr = lane & 15, quad = lane >> 4;
  int c = ct * 16 + lr;            // output col
  int k = kk * 32 + quad * 8 + j;  // K index
  const float* W = (m == 0) ? W0 : ((m == 1) ? W1 : W2);
  u32 p = packsplit(W[k * DIM + c]);
  Whi[i] = (u16)(p & 0xffffu);
  Wlo[i] = (u16)(p >> 16);
}

// =================== gather_gcn ===================

__global__ void gather_gcn(const u16* __restrict__ g,
                           const int* __restrict__ rs, const int* __restrict__ cnt,
                           const int* __restrict__ eidx, const float* __restrict__ rnorm,
                           const float* __restrict__ bias, float* __restrict__ out, int n) {
  int gid = blockIdx.x * 256 + threadIdx.x;
  int i = gid >> 6;
  if (i >= n) return;
  int sub = gid & 63;
  int c = (sub & 31) << 2;
  int start = rs[i], m = cnt[i];
  float4 acc = {0.f, 0.f, 0.f, 0.f};
  if (sub < 32) {   // self term g[i]
    ushort4 pv = *(const ushort4*)(g + ((size_t)i << 7) + c);
    acc.x = bf2f(pv.x); acc.y = bf2f(pv.y);
    acc.z = bf2f(pv.z); acc.w = bf2f(pv.w);
  }
  int j = sub >> 5;
  for (; j + 2 < m; j += 4) {   // two row loads in flight per thread
    int s0 = eidx[start + j], s1 = eidx[start + j + 2];
    ushort4 p0 = *(const ushort4*)(g + ((size_t)s0 << 7) + c);
    ushort4 p1 = *(const ushort4*)(g + ((size_t)s1 << 7) + c);
    acc.x += bf2f(p0.x) + bf2f(p1.x);
    acc.y += bf2f(p0.y) + bf2f(p1.y);
    acc.z += bf2f(p0.z) + bf2f(p1.z);
    acc.w += bf2f(p0.w) + bf2f(p1.w);
  }
  if (j < m) {
    int s = eidx[start + j];
    ushort4 pv = *(const ushort4*)(g + ((size_t)s << 7) + c);
    acc.x += bf2f(pv.x); acc.y += bf2f(pv.y);
    acc.z += bf2f(pv.z); acc.w += bf2f(pv.w);
  }
  acc.x += __shfl_xor(acc.x, 32);
  acc.y += __shfl_xor(acc.y, 32);
  acc.z += __shfl_xor(acc.z, 32);
  acc.w += __shfl_xor(acc.w, 32);
  if (sub < 32) {
    float ri = rnorm[i];
    float4 bv = *(const float4*)(bias + c);
    float4 o;
    o.x = fmaf(ri, acc.x, bv.x);
    o.y = fmaf(ri, acc.y, bv.y);
    o.z = fmaf(ri, acc.z, bv.z);
    o.w = fmaf(ri, acc.w, bv.w);
    *(float4*)(out + (size_t)i * DIM + c) = o;
  }
}

// =================== FUSED stage A + gemm B (v7 = R10 structure + W-load/pack overlap) ===================
// GEMM1: Wd hi+lo BOTH in LDS (64 KB, proven). W loads issued into registers
// BEFORE the A-fragment packsplit (~200 VALU ops hide the L2 latency), ds_write
// after. Held across straight-line code only -- NOT the variable gather loop
// (R8 spill lesson). GEMM2: Wg-hi LDS x2, Wgl L2 x1 (the tolerated L2-W read).
__global__ __launch_bounds__(512) void fused_ab(
    const float* __restrict__ emb,
    const int* __restrict__ rs, const int* __restrict__ cnt, const int* __restrict__ eidx,
    const u16* __restrict__ Wdh, const u16* __restrict__ Wdl,
    const u16* __restrict__ Wgh, const u16* __restrict__ Wgl,
    const float* __restrict__ bd, const float* __restrict__ rnorm,
    u16* __restrict__ obf, int nrows)
{
  __shared__ u16 S[32768];            // 64 KB total
  u32* X = (u32*)(S + 16384);         // byte 32K..48K: x1 quarter slots (during GEMM2)
  const int tid = threadIdx.x;
  const int wave = tid >> 6, lane = tid & 63;
  const int lr = lane & 15, quad = lane >> 4;
  const int rowbase = blockIdx.x * 128 + wave * 16;

  int arow = rowbase + lr;
  if (arow >= nrows) arow = nrows - 1;
  const int start = rs[arow], m = cnt[arow];

  // ---- gather-mean(emb) into GEMM1 A-fragments (no W regs live here) ----
  float4 fa[4], fb[4];
#pragma unroll
  for (int kk = 0; kk < 4; ++kk) {
    fa[kk] = (float4){0.f, 0.f, 0.f, 0.f};
    fb[kk] = (float4){0.f, 0.f, 0.f, 0.f};
  }
  for (int j = 0; j < m; ++j) {
    int s = eidx[start + j];
    const float* rp = emb + (size_t)s * DIM + quad * 8;
#pragma unroll
    for (int kk = 0; kk < 4; ++kk) {
      float4 v0 = *(const float4*)(rp + kk * 32);
      float4 v1 = *(const float4*)(rp + kk * 32 + 4);
      fa[kk].x += v0.x; fa[kk].y += v0.y; fa[kk].z += v0.z; fa[kk].w += v0.w;
      fb[kk].x += v1.x; fb[kk].y += v1.y; fb[kk].z += v1.z; fb[kk].w += v1.w;
    }
  }

  // ---- issue Wd hi+lo loads (latency hides under the pack below) ----
  uint4 wd[8];
  {
    const uint4* H4 = (const uint4*)Wdh;
    const uint4* L4 = (const uint4*)Wdl;
#pragma unroll
    for (int t = 0; t < 4; ++t) {
      wd[t] = H4[tid + t * 512];
      wd[4 + t] = L4[tid + t * 512];
    }
  }

  // ---- pack A-fragments (VALU; overlaps W-load latency) ----
  const float inv = 1.0f / fmaxf((float)m, 1.0f);
  v8s afh[4], afl[4];
#pragma unroll
  for (int kk = 0; kk < 4; ++kk) {
    float vs[8] = {fa[kk].x, fa[kk].y, fa[kk].z, fa[kk].w,
                   fb[kk].x, fb[kk].y, fb[kk].z, fb[kk].w};
#pragma unroll
    for (int j = 0; j < 8; ++j) {
      u32 p = packsplit(vs[j] * inv);
      afh[kk][j] = (short)(p & 0xffffu);
      afl[kk][j] = (short)(p >> 16);
    }
  }

  // ---- write Wd hi+lo to LDS from regs ----
  {
    uint4* S4 = (uint4*)S;
#pragma unroll
    for (int t = 0; t < 4; ++t) {
      S4[tid + t * 512] = wd[t];
      S4[2048 + tid + t * 512] = wd[4 + t];
    }
  }
  __syncthreads();

  // ---- GEMM1: agg1@Wd, both planes from LDS ----
  v4f acc[8];
#pragma unroll
  for (int ct = 0; ct < 8; ++ct) acc[ct] = (v4f){0.f, 0.f, 0.f, 0.f};
#pragma unroll
  for (int kk = 0; kk < 4; ++kk) {
#pragma unroll
    for (int ct = 0; ct < 8; ++ct) {
      const int wo = ((kk * 8 + ct) << 9) + (lane << 3);
      v8s bh = *(const v8s*)(S + wo);
      v8s bl = *(const v8s*)(S + 16384 + wo);
      acc[ct] = __builtin_amdgcn_mfma_f32_16x16x32_bf16(afh[kk], bh, acc[ct], 0, 0, 0);
      acc[ct] = __builtin_amdgcn_mfma_f32_16x16x32_bf16(afh[kk], bl, acc[ct], 0, 0, 0);
      acc[ct] = __builtin_amdgcn_mfma_f32_16x16x32_bf16(afl[kk], bh, acc[ct], 0, 0, 0);
    }
  }
  __syncthreads();   // Wd dead

  // ---- restage Wg-hi into [0:32K) ----
  {
    uint4* S4 = (uint4*)S;
    for (int i = tid; i < 2048; i += 512)
      S4[i] = ((const uint4*)Wgh)[i];
  }

  // ---- x1 quarter 0: x1 = relu(emb + agg1@Wd + bd), cols [0,32) ----
#pragma unroll
  for (int cl = 0; cl < 2; ++cl) {
#pragma unroll
    for (int rg = 0; rg < 4; ++rg) {
      int r = rowbase + quad * 4 + rg;
      int rc = (r < nrows) ? r : (nrows - 1);
      const int col = cl * 16 + lr;
      float v = acc[cl][rg] + bd[col] + emb[(size_t)rc * DIM + col];
      v = fmaxf(v, 0.f);
      int slot = ((rg << 1) | cl) * 64 + (quad << 4) + lr;
      slot ^= ((slot >> 6) & 7) << 2;
      X[wave * 512 + slot] = packsplit(v);
    }
  }
  __syncthreads();   // Wg-hi visible to all waves

  // ---- GEMM2: x1@Wg in 4 K-slices, x1 through LDS quarters ----
  v4f acc2[8];
#pragma unroll
  for (int ct = 0; ct < 8; ++ct) acc2[ct] = (v4f){0.f, 0.f, 0.f, 0.f};
#pragma unroll
  for (int Q = 0; Q < 4; ++Q) {
    // reload kk=Q A-fragments from this wave's private quarter slot
    v8s agh, agl;
    {
      int s0 = ((lr & 3) * 2 + (quad >> 1)) * 64 + ((lr >> 2) << 4) + ((quad & 1) << 3);
      int s1 = s0 + 4;
      s0 ^= ((s0 >> 6) & 7) << 2;
      s1 ^= ((s1 >> 6) & 7) << 2;
      uint4 q0 = *(const uint4*)(X + wave * 512 + s0);
      uint4 q1 = *(const uint4*)(X + wave * 512 + s1);
      u32 u[8] = {q0.x, q0.y, q0.z, q0.w, q1.x, q1.y, q1.z, q1.w};
#pragma unroll
      for (int j = 0; j < 8; ++j) {
        agh[j] = (short)(u[j] & 0xffffu);
        agl[j] = (short)(u[j] >> 16);
      }
    }
#pragma unroll
    for (int ct = 0; ct < 8; ++ct) {
      const int wo = ((Q * 8 + ct) << 9) + (lane << 3);
      v8s bh = *(const v8s*)(S + wo);
      v8s bl = *(const v8s*)(Wgl + wo);
      acc2[ct] = __builtin_amdgcn_mfma_f32_16x16x32_bf16(agh, bh, acc2[ct], 0, 0, 0);
      acc2[ct] = __builtin_amdgcn_mfma_f32_16x16x32_bf16(agh, bl, acc2[ct], 0, 0, 0);
      acc2[ct] = __builtin_amdgcn_mfma_f32_16x16x32_bf16(agl, bh, acc2[ct], 0, 0, 0);
    }
    if (Q < 3) {   // write next quarter (wave-private slot; same-wave DS order)
#pragma unroll
      for (int cl = 0; cl < 2; ++cl) {
        int ct = 2 * (Q + 1) + cl;
#pragma unroll
        for (int rg = 0; rg < 4; ++rg) {
          int r = rowbase + quad * 4 + rg;
          int rc = (r < nrows) ? r : (nrows - 1);
          const int col = ct * 16 + lr;
          float v = acc[ct][rg] + bd[col] + emb[(size_t)rc * DIM + col];
          v = fmaxf(v, 0.f);
          int slot = ((rg << 1) | cl) * 64 + (quad << 4) + lr;
          slot ^= ((slot >> 6) & 7) << 2;
          X[wave * 512 + slot] = packsplit(v);
        }
      }
    }
  }

  __syncthreads();   // all GEMM2 LDS reads done; reuse S[0:32K) as transpose buf

  // ---- epilogue: g = rnorm.*(x1@Wg) -> bf16 row-major via swizzled transpose ----
  // S[lrow*128 + (col ^ ((lrow&7)<<4))]: writes 2-way (free), reads b128-min
  const int lrow0 = wave * 16 + quad * 4;
#pragma unroll
  for (int rg = 0; rg < 4; ++rg) {
    int lrow = lrow0 + rg;
    int r = blockIdx.x * 128 + lrow;
    float sc = rnorm[(r < nrows) ? r : (nrows - 1)];
    const int swz = (lrow & 7) << 4;
#pragma unroll
    for (int ct = 0; ct < 8; ++ct) {
      const int col = ct * 16 + lr;
      S[(lrow << 7) + (col ^ swz)] = f2bf(acc2[ct][rg] * sc);
    }
  }
  __syncthreads();
  const int rowstart = blockIdx.x * 128;
  for (int idx = tid; idx < 2048; idx += 512) {   // 2048 uint4 row stores
    int lrow = idx >> 4, c8 = (idx & 15) << 3;
    int r = rowstart + lrow;
    if (r < nrows) {
      uint4 v = *(const uint4*)&S[(lrow << 7) + (c8 ^ ((lrow & 7) << 4))];
      *(uint4*)(obf + ((size_t)r << 7) + c8) = v;
    }
  }
}

// =================== FUSED stage C: gather-mean + GEMM (both W planes in LDS, R10 form) ===================
__global__ __launch_bounds__(512) void gather_gemm_c(
    const float* __restrict__ x,
    const int* __restrict__ rs, const int* __restrict__ cnt, const int* __restrict__ eidx,
    const u16* __restrict__ Wuh, const u16* __restrict__ Wul,
    const float* __restrict__ bias, float* __restrict__ outf, int nrows)
{
  __shared__ u16 W[2 * DIM * DIM];   // 64 KB: hi | lo, fragment-major
  const int tid = threadIdx.x;
  const int wave = tid >> 6, lane = tid & 63;
  const int lr = lane & 15, quad = lane >> 4;
  const int rowbase = blockIdx.x * 128 + wave * 16;

  int arow = rowbase + lr;
  if (arow >= nrows) arow = nrows - 1;
  const int start = rs[arow], m = cnt[arow];

  float4 fa[4], fb[4];
#pragma unroll
  for (int kk = 0; kk < 4; ++kk) {
    fa[kk] = (float4){0.f, 0.f, 0.f, 0.f};
    fb[kk] = (float4){0.f, 0.f, 0.f, 0.f};
  }
  for (int j = 0; j < m; ++j) {
    int s = eidx[start + j];
    const float* rp = x + (size_t)s * DIM + quad * 8;
#pragma unroll
    for (int kk = 0; kk < 4; ++kk) {
      float4 v0 = *(const float4*)(rp + kk * 32);
      float4 v1 = *(const float4*)(rp + kk * 32 + 4);
      fa[kk].x += v0.x; fa[kk].y += v0.y; fa[kk].z += v0.z; fa[kk].w += v0.w;
      fb[kk].x += v1.x; fb[kk].y += v1.y; fb[kk].z += v1.z; fb[kk].w += v1.w;
    }
  }

  // ---- issue Wu hi+lo loads (latency hides under the pack below) ----
  uint4 wu[8];
  {
    const uint4* H4 = (const uint4*)Wuh;
    const uint4* L4 = (const uint4*)Wul;
#pragma unroll
    for (int t = 0; t < 4; ++t) {
      wu[t] = H4[tid + t * 512];
      wu[4 + t] = L4[tid + t * 512];
    }
  }

  const float inv = 1.0f / fmaxf((float)m, 1.0f);
  v8s afh[4], afl[4];
#pragma unroll
  for (int kk = 0; kk < 4; ++kk) {
    float vs[8] = {fa[kk].x, fa[kk].y, fa[kk].z, fa[kk].w,
                   fb[kk].x, fb[kk].y, fb[kk].z, fb[kk].w};
#pragma unroll
    for (int j = 0; j < 8; ++j) {
      u32 p = packsplit(vs[j] * inv);
      afh[kk][j] = (short)(p & 0xffffu);
      afl[kk][j] = (short)(p >> 16);
    }
  }

  {
    uint4* W4 = (uint4*)W;
#pragma unroll
    for (int t = 0; t < 4; ++t) {
      W4[tid + t * 512] = wu[t];
      W4[2048 + tid + t * 512] = wu[4 + t];
    }
  }
  __syncthreads();

  v4f acc[8];
#pragma unroll
  for (int ct = 0; ct < 8; ++ct) acc[ct] = (v4f){0.f, 0.f, 0.f, 0.f};
#pragma unroll
  for (int kk = 0; kk < 4; ++kk) {
#pragma unroll
    for (int ct = 0; ct < 8; ++ct) {
      const int wo = ((kk * 8 + ct) << 9) + (lane << 3);
      v8s bh = *(const v8s*)(W + wo);
      v8s bl = *(const v8s*)(W + DIM * DIM + wo);
      acc[ct] = __builtin_amdgcn_mfma_f32_16x16x32_bf16(afh[kk], bh, acc[ct], 0, 0, 0);
      acc[ct] = __builtin_amdgcn_mfma_f32_16x16x32_bf16(afh[kk], bl, acc[ct], 0, 0, 0);
      acc[ct] = __builtin_amdgcn_mfma_f32_16x16x32_bf16(afl[kk], bh, acc[ct], 0, 0, 0);
    }
  }

#pragma unroll
  for (int ct = 0; ct < 8; ++ct) {
    const int col = ct * 16 + lr;
    float bv = bias[col];
#pragma unroll
    for (int rg = 0; rg < 4; ++rg) {
      int r = rowbase + quad * 4 + rg;
      if (r < nrows) {
        size_t off = (size_t)r * DIM + col;
        float v = acc[ct][rg] + bv + x[off];
        outf[off] = fmaxf(v, 0.f);
      }
    }
  }
}

// =================== host ===================

extern "C" void kernel_launch(void* const* d_in, const int* in_sizes, int n_in,
                              void* d_out, int out_size, void* d_ws, size_t ws_size,
                              hipStream_t stream) {
  const float* emb = (const float*)d_in[0];
  const float* Wd  = (const float*)d_in[1];
  const float* bd  = (const float*)d_in[2];
  const float* Wg  = (const float*)d_in[3];
  const float* bg  = (const float*)d_in[4];
  const float* Wu  = (const float*)d_in[5];
  const float* bu  = (const float*)d_in[6];
  const int* d2u = (const int*)d_in[7];
  const int* sle = (const int*)d_in[8];
  const int* u2d = (const int*)d_in[9];
  const int E1 = in_sizes[7] / 2;   // 100000
  const int E2 = in_sizes[8] / 2;   // 600000
  const int E3 = in_sizes[9] / 2;   // 100000
  const int Etot = E1 + E2 + E3;
  const int N  = NNODES;
  const size_t nd = (size_t)N * DIM;

  float* xb = (float*)d_ws;        // f32 x2 plane (51.2 MB)
  u16* Gbf  = (u16*)(xb + nd);     // row-major bf16 g plane [nd u16] (25.6 MB)
  int* cnt  = (int*)(Gbf + nd);    // [3N]
  int* bbuf = cnt + 3 * N;         // bucket arrays: bcnt(1024) | gfill(1024) | spare
  int* rs   = bbuf + 3 * 1024;     // [3N]
  int* eidx = rs + 3 * N;          // [Etot]
  float* rnorm = (float*)(eidx + Etot);
  int* bsum = (int*)(rnorm + N);   // unused (layout stability)
  u16* Whi = (u16*)(bsum + 1024);
  u16* Wlo = Whi + 3 * DIM * DIM;
  uint2* pairs = (uint2*)(Wlo + 3 * DIM * DIM);   // [Etot] (6.4 MB)
  int* bcnt  = bbuf;
  int* gfill = bbuf + 1024;

  const int gemm_blocks = (N + 127) / 128;        // 782
  const int ngcn = (N * 64 + 255) / 256;          // 25000 (64 t/node)
  const int nbin = (Etot + EPB - 1) / EPB;        // 391

  // ---- prep (4 dispatches): W planes (+bbuf zero) + bucketed CSR ----
  make_w_planes<<<(3 * DIM * DIM + 255) / 256, 256, 0, stream>>>(Wd, Wg, Wu, Whi, Wlo, bbuf);
  bin_count<<<nbin, 256, 0, stream>>>(d2u, sle, u2d, E1, E2, E3, bcnt);
  bin_fill<<<nbin, 256, 0, stream>>>(d2u, sle, u2d, E1, E2, E3, bcnt, gfill, pairs);
  bucket_build<<<NBUCK, 256, 0, stream>>>(pairs, bcnt, cnt, rs, rnorm, eidx);

  // ---- fused A+B: x1 (LDS-only) ; g = rnorm.*(x1@Wg) -> Gbf ----
  fused_ab<<<gemm_blocks, 512, 0, stream>>>(emb, rs, cnt, eidx,
                                            Whi, Wlo, Whi + DIM * DIM, Wlo + DIM * DIM,
                                            bd, rnorm, Gbf, N);

  // ---- gcn gather: x2 -> xb ----
  gather_gcn<<<ngcn, 256, 0, stream>>>(Gbf, rs + N, cnt + N, eidx, rnorm, bg, xb, N);

  // ---- fused C: out = relu(x2 + mean_gather(x2)@Wu + bu) -> d_out ----
  gather_gemm_c<<<gemm_blocks, 512, 0, stream>>>(xb, rs + 2 * N, cnt + 2 * N, eidx,
                                                 Whi + 2 * DIM * DIM, Wlo + 2 * DIM * DIM,
                                                 bu, (float*)d_out, N);
}

// Round 13
// 270.707 us; speedup vs baseline: 1.0196x; 1.0062x over previous
//
#include <hip/hip_runtime.h>
#include <cstdint>
#include <cstddef>

#define NNODES 100000
#define DIM 128

#define NB3   (3 * NNODES)
#define BSH   9                        // 512 nodes per bucket
#define NBUCK ((NB3 + 511) >> 9)       // 587 buckets
#define EPB   2048                     // edges per block in binning passes

typedef unsigned short u16;
typedef uint32_t u32;
typedef __attribute__((ext_vector_type(8))) short v8s;
typedef __attribute__((ext_vector_type(4))) float v4f;

__device__ __forceinline__ float bf2f(u32 u) {
  union { u32 i; float f; } x; x.i = u << 16; return x.f;
}
__device__ __forceinline__ u16 f2bf(float f) {
  union { float f; u32 i; } x; x.f = f;
  u32 r = x.i + 0x7fffu + ((x.i >> 16) & 1u);  // RNE
  return (u16)(r >> 16);
}
__device__ __forceinline__ u32 packsplit(float f) {
  u16 h = f2bf(f);
  float r = f - bf2f(h);
  u16 l = f2bf(r);
  return (u32)h | ((u32)l << 16);
}

// =================== bucketed CSR build (3 lists concatenated) ===================

__global__ __launch_bounds__(256) void bin_count(const int* __restrict__ d2u,
    const int* __restrict__ sle, const int* __restrict__ u2d,
    int E1, int E2, int E3, int* __restrict__ bcnt) {
  __shared__ int lc[NBUCK];
  const int tid = threadIdx.x;
  for (int i = tid; i < NBUCK; i += 256) lc[i] = 0;
  __syncthreads();
  const int Etot = E1 + E2 + E3;
  const int base = blockIdx.x * EPB;
#pragma unroll
  for (int k = 0; k < EPB; k += 256) {
    int e = base + k + tid;
    if (e < Etot) {
      int idx;
      if (e < E1)            idx = d2u[E1 + e];
      else if (e < E1 + E2)  idx = NNODES + sle[E2 + (e - E1)];
      else                   idx = 2 * NNODES + u2d[E3 + (e - E1 - E2)];
      atomicAdd(&lc[idx >> BSH], 1);
    }
  }
  __syncthreads();
  for (int i = tid; i < NBUCK; i += 256)
    if (lc[i]) atomicAdd(&bcnt[i], lc[i]);
}

// decode edges; per-block LDS histogram; in-block redundant scan of bcnt;
// chunk reservation via gfill (zeroed in make_w_planes); write (dst,src)
// pairs contiguously per bucket.
__global__ __launch_bounds__(256) void bin_fill(const int* __restrict__ d2u,
    const int* __restrict__ sle, const int* __restrict__ u2d,
    int E1, int E2, int E3, const int* __restrict__ bcnt,
    int* __restrict__ gfill, uint2* __restrict__ pairs) {
  __shared__ int lc[NBUCK];   // local count -> chunk cursor
  __shared__ int sc[1024];    // inclusive scan of bcnt
  const int tid = threadIdx.x;
  for (int i = tid; i < NBUCK; i += 256) lc[i] = 0;
  __syncthreads();
  const int Etot = E1 + E2 + E3;
  const int base = blockIdx.x * EPB;
  int vidx[EPB / 256], vsrc[EPB / 256];
#pragma unroll
  for (int k = 0; k < EPB / 256; ++k) {
    int e = base + k * 256 + tid;
    int idx = -1, src = 0;
    if (e < Etot) {
      if (e < E1)            { idx = d2u[E1 + e];                          src = d2u[e]; }
      else if (e < E1 + E2)  { int q = e - E1;      idx = NNODES + sle[E2 + q];      src = sle[q]; }
      else                   { int q = e - E1 - E2; idx = 2 * NNODES + u2d[E3 + q];  src = u2d[q]; }
      atomicAdd(&lc[idx >> BSH], 1);
    }
    vidx[k] = idx; vsrc[k] = src;
  }
  __syncthreads();
  // in-block scan of bcnt -> sc (inclusive)
  for (int i = tid; i < 1024; i += 256) sc[i] = (i < NBUCK) ? bcnt[i] : 0;
  __syncthreads();
  for (int off = 1; off < 1024; off <<= 1) {
    int vals[4];
#pragma unroll
    for (int j = 0; j < 4; ++j) { int i = tid + j * 256; vals[j] = (i >= off) ? sc[i - off] : 0; }
    __syncthreads();
#pragma unroll
    for (int j = 0; j < 4; ++j) { int i = tid + j * 256; sc[i] += vals[j]; }
    __syncthreads();
  }
  // per-block contiguous reservation: brs[i] = sc[i]-bcnt[i]
  for (int i = tid; i < NBUCK; i += 256) {
    int c = lc[i];
    if (c) lc[i] = (sc[i] - bcnt[i]) + atomicAdd(&gfill[i], c);
  }
  __syncthreads();
#pragma unroll
  for (int k = 0; k < EPB / 256; ++k) {
    int idx = vidx[k];
    if (idx >= 0) {
      int pos = atomicAdd(&lc[idx >> BSH], 1);
      pairs[pos] = make_uint2((unsigned)idx, (unsigned)vsrc[k]);
    }
  }
}

// one block per bucket: self-computed bucket base -> histogram -> LDS prefix
// -> cnt/rs/rnorm coalesced -> eidx scatter.
__global__ __launch_bounds__(256) void bucket_build(const uint2* __restrict__ pairs,
    const int* __restrict__ bcnt,
    int* __restrict__ cnt, int* __restrict__ rs, float* __restrict__ rnorm,
    int* __restrict__ eidx) {
  __shared__ int c[512];
  __shared__ int cur[512];
  __shared__ int wsum[4];
  const int tid = threadIdx.x;
  const int b = blockIdx.x;
  // s = sum_{i<b} bcnt[i]
  int part = 0;
  for (int i = tid; i < b; i += 256) part += bcnt[i];
#pragma unroll
  for (int o = 32; o > 0; o >>= 1) part += __shfl_down(part, o, 64);
  if ((tid & 63) == 0) wsum[tid >> 6] = part;
  for (int i = tid; i < 512; i += 256) c[i] = 0;
  __syncthreads();
  const int s = wsum[0] + wsum[1] + wsum[2] + wsum[3];
  const int m = bcnt[b];
  for (int k = tid; k < m; k += 256) {
    uint2 p = pairs[s + k];
    atomicAdd(&c[p.x & 511], 1);
  }
  __syncthreads();
  // exclusive prefix over the bucket's 512 counts (2 per thread + wave scan)
  const int v0 = c[tid * 2], v1 = c[tid * 2 + 1];
  const int tsum = v0 + v1;
  const int lane = tid & 63, wid = tid >> 6;
  int x = tsum;
  for (int off = 1; off < 64; off <<= 1) {
    int y = __shfl_up(x, off, 64);
    if (lane >= off) x += y;
  }
  if (lane == 63) wsum[wid] = x;
  __syncthreads();
  int woff = 0;
  for (int w = 0; w < wid; ++w) woff += wsum[w];
  const int excl = woff + x - tsum;
  const int node0 = b << BSH;
  const int g0 = node0 + tid * 2, g1 = g0 + 1;
  const int r0 = s + excl, r1 = s + excl + v0;
  if (g0 < NB3) {
    cnt[g0] = v0; rs[g0] = r0; cur[tid * 2] = r0;
    if (g0 >= NNODES && g0 < 2 * NNODES) rnorm[g0 - NNODES] = rsqrtf((float)v0 + 1.0f);
  }
  if (g1 < NB3) {
    cnt[g1] = v1; rs[g1] = r1; cur[tid * 2 + 1] = r1;
    if (g1 >= NNODES && g1 < 2 * NNODES) rnorm[g1 - NNODES] = rsqrtf((float)v1 + 1.0f);
  }
  __syncthreads();
  for (int k = tid; k < m; k += 256) {
    uint2 p = pairs[s + k];
    int pos = atomicAdd(&cur[p.x & 511], 1);
    eidx[pos] = (int)p.y;
  }
}

// W planes in FRAGMENT-MAJOR order: slab (kk,ct) of 64 lanes x 8 u16 = 1 KB
// contiguous. Bit-exact same per-lane values as the original LDS layout.
// i bits: [2:0]=j  [8:3]=lane  [11:9]=ct  [13:12]=kk  [15:14]=m
// Also zeroes bcnt[0:1024) + gfill[0:1024) (bbuf[0:2048)).
__global__ void make_w_planes(const float* __restrict__ W0, const float* __restrict__ W1,
                              const float* __restrict__ W2,
                              u16* __restrict__ Whi, u16* __restrict__ Wlo,
                              int* __restrict__ bbuf) {
  int i = blockIdx.x * 256 + threadIdx.x;
  if (i < 2048) bbuf[i] = 0;
  if (i >= 3 * DIM * DIM) return;
  int j = i & 7, lane = (i >> 3) & 63, ct = (i >> 9) & 7, kk = (i >> 12) & 3, m = i >> 14;
  int lr = lane & 15, quad = lane >> 4;
  int c = ct * 16 + lr;            // output col
  int k = kk * 32 + quad * 8 + j;  // K index
  const float* W = (m == 0) ? W0 : ((m == 1) ? W1 : W2);
  u32 p = packsplit(W[k * DIM + c]);
  Whi[i] = (u16)(p & 0xffffu);
  Wlo[i] = (u16)(p >> 16);
}

// =================== gather_gcn (4-deep edge pipeline) ===================

__global__ void gather_gcn(const u16* __restrict__ g,
                           const int* __restrict__ rs, const int* __restrict__ cnt,
                           const int* __restrict__ eidx, const float* __restrict__ rnorm,
                           const float* __restrict__ bias, float* __restrict__ out, int n) {
  int gid = blockIdx.x * 256 + threadIdx.x;
  int i = gid >> 6;
  if (i >= n) return;
  int sub = gid & 63;
  int c = (sub & 31) << 2;
  int start = rs[i], m = cnt[i];
  float4 acc = {0.f, 0.f, 0.f, 0.f};
  if (sub < 32) {   // self term g[i]
    ushort4 pv = *(const ushort4*)(g + ((size_t)i << 7) + c);
    acc.x = bf2f(pv.x); acc.y = bf2f(pv.y);
    acc.z = bf2f(pv.z); acc.w = bf2f(pv.w);
  }
  int j = sub >> 5;
  for (; j + 6 < m; j += 8) {   // four row loads in flight per thread
    int s0 = eidx[start + j], s1 = eidx[start + j + 2];
    int s2 = eidx[start + j + 4], s3 = eidx[start + j + 6];
    ushort4 p0 = *(const ushort4*)(g + ((size_t)s0 << 7) + c);
    ushort4 p1 = *(const ushort4*)(g + ((size_t)s1 << 7) + c);
    ushort4 p2 = *(const ushort4*)(g + ((size_t)s2 << 7) + c);
    ushort4 p3 = *(const ushort4*)(g + ((size_t)s3 << 7) + c);
    acc.x += (bf2f(p0.x) + bf2f(p1.x)) + (bf2f(p2.x) + bf2f(p3.x));
    acc.y += (bf2f(p0.y) + bf2f(p1.y)) + (bf2f(p2.y) + bf2f(p3.y));
    acc.z += (bf2f(p0.z) + bf2f(p1.z)) + (bf2f(p2.z) + bf2f(p3.z));
    acc.w += (bf2f(p0.w) + bf2f(p1.w)) + (bf2f(p2.w) + bf2f(p3.w));
  }
  for (; j + 2 < m; j += 4) {   // two row loads in flight
    int s0 = eidx[start + j], s1 = eidx[start + j + 2];
    ushort4 p0 = *(const ushort4*)(g + ((size_t)s0 << 7) + c);
    ushort4 p1 = *(const ushort4*)(g + ((size_t)s1 << 7) + c);
    acc.x += bf2f(p0.x) + bf2f(p1.x);
    acc.y += bf2f(p0.y) + bf2f(p1.y);
    acc.z += bf2f(p0.z) + bf2f(p1.z);
    acc.w += bf2f(p0.w) + bf2f(p1.w);
  }
  if (j < m) {
    int s = eidx[start + j];
    ushort4 pv = *(const ushort4*)(g + ((size_t)s << 7) + c);
    acc.x += bf2f(pv.x); acc.y += bf2f(pv.y);
    acc.z += bf2f(pv.z); acc.w += bf2f(pv.w);
  }
  acc.x += __shfl_xor(acc.x, 32);
  acc.y += __shfl_xor(acc.y, 32);
  acc.z += __shfl_xor(acc.z, 32);
  acc.w += __shfl_xor(acc.w, 32);
  if (sub < 32) {
    float ri = rnorm[i];
    float4 bv = *(const float4*)(bias + c);
    float4 o;
    o.x = fmaf(ri, acc.x, bv.x);
    o.y = fmaf(ri, acc.y, bv.y);
    o.z = fmaf(ri, acc.z, bv.z);
    o.w = fmaf(ri, acc.w, bv.w);
    *(float4*)(out + (size_t)i * DIM + c) = o;
  }
}

// 2-way unrolled gather-mean: 16 row-loads in flight (halves the dependent
// chain; Poisson(1) degrees -> wave max-degree 4-5 drops to 2-3 rounds).
__device__ __forceinline__ void gather_mean_frag(
    const float* __restrict__ x, const int* __restrict__ eidx,
    int start, int m, int quad, float4 fa[4], float4 fb[4]) {
#pragma unroll
  for (int kk = 0; kk < 4; ++kk) {
    fa[kk] = (float4){0.f, 0.f, 0.f, 0.f};
    fb[kk] = (float4){0.f, 0.f, 0.f, 0.f};
  }
  int j = 0;
  for (; j + 1 < m; j += 2) {
    int s0 = eidx[start + j], s1 = eidx[start + j + 1];
    const float* r0 = x + (size_t)s0 * DIM + quad * 8;
    const float* r1 = x + (size_t)s1 * DIM + quad * 8;
#pragma unroll
    for (int kk = 0; kk < 4; ++kk) {
      float4 a0 = *(const float4*)(r0 + kk * 32);
      float4 a1 = *(const float4*)(r0 + kk * 32 + 4);
      float4 b0 = *(const float4*)(r1 + kk * 32);
      float4 b1 = *(const float4*)(r1 + kk * 32 + 4);
      fa[kk].x += a0.x + b0.x; fa[kk].y += a0.y + b0.y;
      fa[kk].z += a0.z + b0.z; fa[kk].w += a0.w + b0.w;
      fb[kk].x += a1.x + b1.x; fb[kk].y += a1.y + b1.y;
      fb[kk].z += a1.z + b1.z; fb[kk].w += a1.w + b1.w;
    }
  }
  if (j < m) {
    int s = eidx[start + j];
    const float* rp = x + (size_t)s * DIM + quad * 8;
#pragma unroll
    for (int kk = 0; kk < 4; ++kk) {
      float4 v0 = *(const float4*)(rp + kk * 32);
      float4 v1 = *(const float4*)(rp + kk * 32 + 4);
      fa[kk].x += v0.x; fa[kk].y += v0.y; fa[kk].z += v0.z; fa[kk].w += v0.w;
      fb[kk].x += v1.x; fb[kk].y += v1.y; fb[kk].z += v1.z; fb[kk].w += v1.w;
    }
  }
}

// =================== FUSED stage A + gemm B (v8 = v7 + unrolled gather) ===================
__global__ __launch_bounds__(512) void fused_ab(
    const float* __restrict__ emb,
    const int* __restrict__ rs, const int* __restrict__ cnt, const int* __restrict__ eidx,
    const u16* __restrict__ Wdh, const u16* __restrict__ Wdl,
    const u16* __restrict__ Wgh, const u16* __restrict__ Wgl,
    const float* __restrict__ bd, const float* __restrict__ rnorm,
    u16* __restrict__ obf, int nrows)
{
  __shared__ u16 S[32768];            // 64 KB total
  u32* X = (u32*)(S + 16384);         // byte 32K..48K: x1 quarter slots (during GEMM2)
  const int tid = threadIdx.x;
  const int wave = tid >> 6, lane = tid & 63;
  const int lr = lane & 15, quad = lane >> 4;
  const int rowbase = blockIdx.x * 128 + wave * 16;

  int arow = rowbase + lr;
  if (arow >= nrows) arow = nrows - 1;
  const int start = rs[arow], m = cnt[arow];

  // ---- gather-mean(emb) into GEMM1 A-fragments (2-way unrolled) ----
  float4 fa[4], fb[4];
  gather_mean_frag(emb, eidx, start, m, quad, fa, fb);

  // ---- issue Wd hi+lo loads (latency hides under the pack below) ----
  uint4 wd[8];
  {
    const uint4* H4 = (const uint4*)Wdh;
    const uint4* L4 = (const uint4*)Wdl;
#pragma unroll
    for (int t = 0; t < 4; ++t) {
      wd[t] = H4[tid + t * 512];
      wd[4 + t] = L4[tid + t * 512];
    }
  }

  // ---- pack A-fragments (VALU; overlaps W-load latency) ----
  const float inv = 1.0f / fmaxf((float)m, 1.0f);
  v8s afh[4], afl[4];
#pragma unroll
  for (int kk = 0; kk < 4; ++kk) {
    float vs[8] = {fa[kk].x, fa[kk].y, fa[kk].z, fa[kk].w,
                   fb[kk].x, fb[kk].y, fb[kk].z, fb[kk].w};
#pragma unroll
    for (int j = 0; j < 8; ++j) {
      u32 p = packsplit(vs[j] * inv);
      afh[kk][j] = (short)(p & 0xffffu);
      afl[kk][j] = (short)(p >> 16);
    }
  }

  // ---- write Wd hi+lo to LDS from regs ----
  {
    uint4* S4 = (uint4*)S;
#pragma unroll
    for (int t = 0; t < 4; ++t) {
      S4[tid + t * 512] = wd[t];
      S4[2048 + tid + t * 512] = wd[4 + t];
    }
  }
  __syncthreads();

  // ---- GEMM1: agg1@Wd, both planes from LDS ----
  v4f acc[8];
#pragma unroll
  for (int ct = 0; ct < 8; ++ct) acc[ct] = (v4f){0.f, 0.f, 0.f, 0.f};
#pragma unroll
  for (int kk = 0; kk < 4; ++kk) {
#pragma unroll
    for (int ct = 0; ct < 8; ++ct) {
      const int wo = ((kk * 8 + ct) << 9) + (lane << 3);
      v8s bh = *(const v8s*)(S + wo);
      v8s bl = *(const v8s*)(S + 16384 + wo);
      acc[ct] = __builtin_amdgcn_mfma_f32_16x16x32_bf16(afh[kk], bh, acc[ct], 0, 0, 0);
      acc[ct] = __builtin_amdgcn_mfma_f32_16x16x32_bf16(afh[kk], bl, acc[ct], 0, 0, 0);
      acc[ct] = __builtin_amdgcn_mfma_f32_16x16x32_bf16(afl[kk], bh, acc[ct], 0, 0, 0);
    }
  }
  __syncthreads();   // Wd dead

  // ---- restage Wg-hi into [0:32K) ----
  {
    uint4* S4 = (uint4*)S;
    for (int i = tid; i < 2048; i += 512)
      S4[i] = ((const uint4*)Wgh)[i];
  }

  // ---- x1 quarter 0: x1 = relu(emb + agg1@Wd + bd), cols [0,32) ----
#pragma unroll
  for (int cl = 0; cl < 2; ++cl) {
#pragma unroll
    for (int rg = 0; rg < 4; ++rg) {
      int r = rowbase + quad * 4 + rg;
      int rc = (r < nrows) ? r : (nrows - 1);
      const int col = cl * 16 + lr;
      float v = acc[cl][rg] + bd[col] + emb[(size_t)rc * DIM + col];
      v = fmaxf(v, 0.f);
      int slot = ((rg << 1) | cl) * 64 + (quad << 4) + lr;
      slot ^= ((slot >> 6) & 7) << 2;
      X[wave * 512 + slot] = packsplit(v);
    }
  }
  __syncthreads();   // Wg-hi visible to all waves

  // ---- GEMM2: x1@Wg in 4 K-slices, x1 through LDS quarters ----
  v4f acc2[8];
#pragma unroll
  for (int ct = 0; ct < 8; ++ct) acc2[ct] = (v4f){0.f, 0.f, 0.f, 0.f};
#pragma unroll
  for (int Q = 0; Q < 4; ++Q) {
    // reload kk=Q A-fragments from this wave's private quarter slot
    v8s agh, agl;
    {
      int s0 = ((lr & 3) * 2 + (quad >> 1)) * 64 + ((lr >> 2) << 4) + ((quad & 1) << 3);
      int s1 = s0 + 4;
      s0 ^= ((s0 >> 6) & 7) << 2;
      s1 ^= ((s1 >> 6) & 7) << 2;
      uint4 q0 = *(const uint4*)(X + wave * 512 + s0);
      uint4 q1 = *(const uint4*)(X + wave * 512 + s1);
      u32 u[8] = {q0.x, q0.y, q0.z, q0.w, q1.x, q1.y, q1.z, q1.w};
#pragma unroll
      for (int j = 0; j < 8; ++j) {
        agh[j] = (short)(u[j] & 0xffffu);
        agl[j] = (short)(u[j] >> 16);
      }
    }
#pragma unroll
    for (int ct = 0; ct < 8; ++ct) {
      const int wo = ((Q * 8 + ct) << 9) + (lane << 3);
      v8s bh = *(const v8s*)(S + wo);
      v8s bl = *(const v8s*)(Wgl + wo);
      acc2[ct] = __builtin_amdgcn_mfma_f32_16x16x32_bf16(agh, bh, acc2[ct], 0, 0, 0);
      acc2[ct] = __builtin_amdgcn_mfma_f32_16x16x32_bf16(agh, bl, acc2[ct], 0, 0, 0);
      acc2[ct] = __builtin_amdgcn_mfma_f32_16x16x32_bf16(agl, bh, acc2[ct], 0, 0, 0);
    }
    if (Q < 3) {   // write next quarter (wave-private slot; same-wave DS order)
#pragma unroll
      for (int cl = 0; cl < 2; ++cl) {
        int ct = 2 * (Q + 1) + cl;
#pragma unroll
        for (int rg = 0; rg < 4; ++rg) {
          int r = rowbase + quad * 4 + rg;
          int rc = (r < nrows) ? r : (nrows - 1);
          const int col = ct * 16 + lr;
          float v = acc[ct][rg] + bd[col] + emb[(size_t)rc * DIM + col];
          v = fmaxf(v, 0.f);
          int slot = ((rg << 1) | cl) * 64 + (quad << 4) + lr;
          slot ^= ((slot >> 6) & 7) << 2;
          X[wave * 512 + slot] = packsplit(v);
        }
      }
    }
  }

  __syncthreads();   // all GEMM2 LDS reads done; reuse S[0:32K) as transpose buf

  // ---- epilogue: g = rnorm.*(x1@Wg) -> bf16 row-major via swizzled transpose ----
  const int lrow0 = wave * 16 + quad * 4;
#pragma unroll
  for (int rg = 0; rg < 4; ++rg) {
    int lrow = lrow0 + rg;
    int r = blockIdx.x * 128 + lrow;
    float sc = rnorm[(r < nrows) ? r : (nrows - 1)];
    const int swz = (lrow & 7) << 4;
#pragma unroll
    for (int ct = 0; ct < 8; ++ct) {
      const int col = ct * 16 + lr;
      S[(lrow << 7) + (col ^ swz)] = f2bf(acc2[ct][rg] * sc);
    }
  }
  __syncthreads();
  const int rowstart = blockIdx.x * 128;
  for (int idx = tid; idx < 2048; idx += 512) {   // 2048 uint4 row stores
    int lrow = idx >> 4, c8 = (idx & 15) << 3;
    int r = rowstart + lrow;
    if (r < nrows) {
      uint4 v = *(const uint4*)&S[(lrow << 7) + (c8 ^ ((lrow & 7) << 4))];
      *(uint4*)(obf + ((size_t)r << 7) + c8) = v;
    }
  }
}

// =================== FUSED stage C: gather-mean + GEMM (both W planes LDS, unrolled gather) ===================
__global__ __launch_bounds__(512) void gather_gemm_c(
    const float* __restrict__ x,
    const int* __restrict__ rs, const int* __restrict__ cnt, const int* __restrict__ eidx,
    const u16* __restrict__ Wuh, const u16* __restrict__ Wul,
    const float* __restrict__ bias, float* __restrict__ outf, int nrows)
{
  __shared__ u16 W[2 * DIM * DIM];   // 64 KB: hi | lo, fragment-major
  const int tid = threadIdx.x;
  const int wave = tid >> 6, lane = tid & 63;
  const int lr = lane & 15, quad = lane >> 4;
  const int rowbase = blockIdx.x * 128 + wave * 16;

  int arow = rowbase + lr;
  if (arow >= nrows) arow = nrows - 1;
  const int start = rs[arow], m = cnt[arow];

  float4 fa[4], fb[4];
  gather_mean_frag(x, eidx, start, m, quad, fa, fb);

  // ---- issue Wu hi+lo loads (latency hides under the pack below) ----
  uint4 wu[8];
  {
    const uint4* H4 = (const uint4*)Wuh;
    const uint4* L4 = (const uint4*)Wul;
#pragma unroll
    for (int t = 0; t < 4; ++t) {
      wu[t] = H4[tid + t * 512];
      wu[4 + t] = L4[tid + t * 512];
    }
  }

  const float inv = 1.0f / fmaxf((float)m, 1.0f);
  v8s afh[4], afl[4];
#pragma unroll
  for (int kk = 0; kk < 4; ++kk) {
    float vs[8] = {fa[kk].x, fa[kk].y, fa[kk].z, fa[kk].w,
                   fb[kk].x, fb[kk].y, fb[kk].z, fb[kk].w};
#pragma unroll
    for (int j = 0; j < 8; ++j) {
      u32 p = packsplit(vs[j] * inv);
      afh[kk][j] = (short)(p & 0xffffu);
      afl[kk][j] = (short)(p >> 16);
    }
  }

  {
    uint4* W4 = (uint4*)W;
#pragma unroll
    for (int t = 0; t < 4; ++t) {
      W4[tid + t * 512] = wu[t];
      W4[2048 + tid + t * 512] = wu[4 + t];
    }
  }
  __syncthreads();

  v4f acc[8];
#pragma unroll
  for (int ct = 0; ct < 8; ++ct) acc[ct] = (v4f){0.f, 0.f, 0.f, 0.f};
#pragma unroll
  for (int kk = 0; kk < 4; ++kk) {
#pragma unroll
    for (int ct = 0; ct < 8; ++ct) {
      const int wo = ((kk * 8 + ct) << 9) + (lane << 3);
      v8s bh = *(const v8s*)(W + wo);
      v8s bl = *(const v8s*)(W + DIM * DIM + wo);
      acc[ct] = __builtin_amdgcn_mfma_f32_16x16x32_bf16(afh[kk], bh, acc[ct], 0, 0, 0);
      acc[ct] = __builtin_amdgcn_mfma_f32_16x16x32_bf16(afh[kk], bl, acc[ct], 0, 0, 0);
      acc[ct] = __builtin_amdgcn_mfma_f32_16x16x32_bf16(afl[kk], bh, acc[ct], 0, 0, 0);
    }
  }

#pragma unroll
  for (int ct = 0; ct < 8; ++ct) {
    const int col = ct * 16 + lr;
    float bv = bias[col];
#pragma unroll
    for (int rg = 0; rg < 4; ++rg) {
      int r = rowbase + quad * 4 + rg;
      if (r < nrows) {
        size_t off = (size_t)r * DIM + col;
        float v = acc[ct][rg] + bv + x[off];
        outf[off] = fmaxf(v, 0.f);
      }
    }
  }
}

// =================== host ===================

extern "C" void kernel_launch(void* const* d_in, const int* in_sizes, int n_in,
                              void* d_out, int out_size, void* d_ws, size_t ws_size,
                              hipStream_t stream) {
  const float* emb = (const float*)d_in[0];
  const float* Wd  = (const float*)d_in[1];
  const float* bd  = (const float*)d_in[2];
  const float* Wg  = (const float*)d_in[3];
  const float* bg  = (const float*)d_in[4];
  const float* Wu  = (const float*)d_in[5];
  const float* bu  = (const float*)d_in[6];
  const int* d2u = (const int*)d_in[7];
  const int* sle = (const int*)d_in[8];
  const int* u2d = (const int*)d_in[9];
  const int E1 = in_sizes[7] / 2;   // 100000
  const int E2 = in_sizes[8] / 2;   // 600000
  const int E3 = in_sizes[9] / 2;   // 100000
  const int Etot = E1 + E2 + E3;
  const int N  = NNODES;
  const size_t nd = (size_t)N * DIM;

  float* xb = (float*)d_ws;        // f32 x2 plane (51.2 MB)
  u16* Gbf  = (u16*)(xb + nd);     // row-major bf16 g plane [nd u16] (25.6 MB)
  int* cnt  = (int*)(Gbf + nd);    // [3N]
  int* bbuf = cnt + 3 * N;         // bucket arrays: bcnt(1024) | gfill(1024) | spare
  int* rs   = bbuf + 3 * 1024;     // [3N]
  int* eidx = rs + 3 * N;          // [Etot]
  float* rnorm = (float*)(eidx + Etot);
  int* bsum = (int*)(rnorm + N);   // unused (layout stability)
  u16* Whi = (u16*)(bsum + 1024);
  u16* Wlo = Whi + 3 * DIM * DIM;
  uint2* pairs = (uint2*)(Wlo + 3 * DIM * DIM);   // [Etot] (6.4 MB)
  int* bcnt  = bbuf;
  int* gfill = bbuf + 1024;

  const int gemm_blocks = (N + 127) / 128;        // 782
  const int ngcn = (N * 64 + 255) / 256;          // 25000 (64 t/node)
  const int nbin = (Etot + EPB - 1) / EPB;        // 391

  // ---- prep (4 dispatches): W planes (+bbuf zero) + bucketed CSR ----
  make_w_planes<<<(3 * DIM * DIM + 255) / 256, 256, 0, stream>>>(Wd, Wg, Wu, Whi, Wlo, bbuf);
  bin_count<<<nbin, 256, 0, stream>>>(d2u, sle, u2d, E1, E2, E3, bcnt);
  bin_fill<<<nbin, 256, 0, stream>>>(d2u, sle, u2d, E1, E2, E3, bcnt, gfill, pairs);
  bucket_build<<<NBUCK, 256, 0, stream>>>(pairs, bcnt, cnt, rs, rnorm, eidx);

  // ---- fused A+B: x1 (LDS-only) ; g = rnorm.*(x1@Wg) -> Gbf ----
  fused_ab<<<gemm_blocks, 512, 0, stream>>>(emb, rs, cnt, eidx,
                                            Whi, Wlo, Whi + DIM * DIM, Wlo + DIM * DIM,
                                            bd, rnorm, Gbf, N);

  // ---- gcn gather: x2 -> xb ----
  gather_gcn<<<ngcn, 256, 0, stream>>>(Gbf, rs + N, cnt + N, eidx, rnorm, bg, xb, N);

  // ---- fused C: out = relu(x2 + mean_gather(x2)@Wu + bu) -> d_out ----
  gather_gemm_c<<<gemm_blocks, 512, 0, stream>>>(xb, rs + 2 * N, cnt + 2 * N, eidx,
                                                 Whi + 2 * DIM * DIM, Wlo + 2 * DIM * DIM,
                                                 bu, (float*)d_out, N);
}